// Round 6
// baseline (453.098 us; speedup 1.0000x reference)
//
#include <hip/hip_runtime.h>

// ---------------------------------------------------------------------------
// MR_GNN: 2x (RGCN + GroupEnhance) + linear head.
// R8 (resubmit; R5 bench was an infra failure — container acquire died, no
// kernel error/absmax/profile was produced):
//  (a) REL=1 gather quarter-specialization: CSR is (node,rel)-sorted, so
//      quarter q owns relation-q's segment. 1 fma4/edge (was 4 masked), no
//      quad_reduce (lane(q,m) holds agg_q[m-slice] = store layout).
//  (b) head GEMM fused into layer-2 group GEMM (MODE 3): g-tile staged to
//      LDS after the k-loop, outW staged to Bs, in-block 64->32 mini-GEMM.
//      Kills gbuf write + head's re-reads + one launch.
// CSR build and REL=0 gather unchanged from the 441us R7 kernel.
// ---------------------------------------------------------------------------

#define PART_EPB 2048  // edges per partition/hist block (256 thr x 8)

// ---- CSR build, pass A1: per-bucket edge counts (bucket = dst >> 8) ----
__global__ __launch_bounds__(256) void bucket_hist(const int* __restrict__ ei,
                                                   int* __restrict__ bcnt,
                                                   int E, int NB) {
    __shared__ int h[1024];
    for (int i = threadIdx.x; i < 1024; i += 256) h[i] = 0;
    __syncthreads();
    int base = blockIdx.x * PART_EPB;
#pragma unroll
    for (int k = 0; k < PART_EPB / 256; ++k) {
        int e = base + k * 256 + threadIdx.x;
        if (e < E) atomicAdd(&h[ei[E + e] >> 8], 1);
    }
    __syncthreads();
    for (int i = threadIdx.x; i < NB; i += 256)
        if (h[i]) atomicAdd(&bcnt[i], h[i]);
}

// ---- pass A-scan: exclusive scan of NB (<=1024) bucket counts ----
__global__ __launch_bounds__(1024) void bucket_scan(const int* __restrict__ bcnt,
                                                    int* __restrict__ bofs,
                                                    int* __restrict__ bcur,
                                                    int NB, int E) {
    __shared__ int lds[1024];
    int tid = threadIdx.x;
    int v = (tid < NB) ? bcnt[tid] : 0;
    lds[tid] = v;
    __syncthreads();
    int acc = v;
    for (int off = 1; off < 1024; off <<= 1) {
        int t = (tid >= off) ? lds[tid - off] : 0;
        __syncthreads();
        acc += t;
        lds[tid] = acc;
        __syncthreads();
    }
    int excl = acc - v;
    if (tid < NB) { bofs[tid] = excl; bcur[tid] = excl; }
    if (tid == 0) bofs[NB] = E;
}

// ---- pass A2: block-aggregated partition into bucket streams ----
__global__ __launch_bounds__(256) void partition(const int* __restrict__ ei,
                                                 const int* __restrict__ et,
                                                 const float* __restrict__ ew,
                                                 int* __restrict__ gcur,
                                                 int2* __restrict__ recA,
                                                 int* __restrict__ recB,
                                                 int E, int NB) {
    __shared__ int hist[1024];
    __shared__ int base[1024];
    const int tid = threadIdx.x;
    const int blockBase = blockIdx.x * PART_EPB;
    for (int i = tid; i < 1024; i += 256) hist[i] = 0;
    __syncthreads();
#pragma unroll
    for (int k = 0; k < PART_EPB / 256; ++k) {
        int e = blockBase + k * 256 + tid;
        if (e < E) atomicAdd(&hist[ei[E + e] >> 8], 1);
    }
    __syncthreads();
    for (int i = tid; i < NB; i += 256) {
        int h = hist[i];
        base[i] = h ? atomicAdd(&gcur[i], h) : 0;
    }
    __syncthreads();
    for (int i = tid; i < 1024; i += 256) hist[i] = 0;  // reuse as run cursor
    __syncthreads();
#pragma unroll
    for (int k = 0; k < PART_EPB / 256; ++k) {
        int e = blockBase + k * 256 + tid;
        if (e >= E) continue;
        int dst = ei[E + e];
        int b = dst >> 8;
        int pos = base[b] + atomicAdd(&hist[b], 1);
        recA[pos] = make_int2(ei[e], __float_as_int(ew[e]));
        recB[pos] = dst * 4 + et[e];
    }
}

// ---- pass B: per-bucket (node,rel) hist + scan in LDS, write rp2 + pw ----
__global__ __launch_bounds__(256) void bucket_fill(
    const int2* __restrict__ recA, const int* __restrict__ recB,
    const int* __restrict__ bofs, int* __restrict__ rp2, int2* __restrict__ pw,
    int N) {
    __shared__ int cnt[1024];
    __shared__ int cur[1024];
    __shared__ int wsum[4];
    const int b = blockIdx.x;
    const int tid = threadIdx.x;
    const int beg = bofs[b], end = bofs[b + 1];
    const int rebase = b << 10;  // base index in (dst*4+rel) space
    for (int j = 0; j < 4; ++j) cnt[tid * 4 + j] = 0;
    __syncthreads();
    for (int i = beg + tid; i < end; i += 256)
        atomicAdd(&cnt[recB[i] - rebase], 1);
    __syncthreads();
    int v[4];
    int s = 0;
#pragma unroll
    for (int j = 0; j < 4; ++j) { v[j] = cnt[tid * 4 + j]; s += v[j]; }
    int lane = tid & 63, wid = tid >> 6;
    int ws = s;
#pragma unroll
    for (int off = 1; off < 64; off <<= 1) {
        int t = __shfl_up(ws, off);
        if (lane >= off) ws += t;
    }
    if (lane == 63) wsum[wid] = ws;
    __syncthreads();
    int wb = 0;
    for (int w = 0; w < wid; ++w) wb += wsum[w];
    int run = beg + wb + ws - s;
#pragma unroll
    for (int j = 0; j < 4; ++j) {
        int idx = rebase + tid * 4 + j;
        if (idx <= 4 * N) rp2[idx] = run;
        cur[tid * 4 + j] = run;
        run += v[j];
    }
    __syncthreads();
    for (int i = beg + tid; i < end; i += 256) {
        int l = recB[i] - rebase;
        int p = atomicAdd(&cur[l], 1);
        pw[p] = recA[i];
    }
}

__device__ __forceinline__ float4 quad_reduce(float4 a) {
#pragma unroll
    for (int off = 16; off < 64; off <<= 1) {
        a.x += __shfl_xor(a.x, off);
        a.y += __shfl_xor(a.y, off);
        a.z += __shfl_xor(a.z, off);
        a.w += __shfl_xor(a.w, off);
    }
    return a;
}

__device__ __forceinline__ void fma4(float4& a, float w, const float4& x) {
    a.x += w * x.x; a.y += w * x.y; a.z += w * x.z; a.w += w * x.w;
}

// ---------------------------------------------------------------------------
// Gather. One wave per node; lane = 16*q + m; m indexes a float4 of the
// 64-feature row.
// REL=1: quarter q owns relation-q's CSR segment (consecutive edges),
//        predicated 4-slot inner loop, single fma4 per edge. Lane(q,m)
//        ends with agg_q[m*4..+4) -> direct store, no reduce.
//        out: N x 256.
// REL=0: quarters stride-4 over the unified [s0,s4) range, 4 accumulator
//        chains, quad_reduce; quarter 0 stores. out: N x 64.
// ---------------------------------------------------------------------------
template <int REL>
__global__ __launch_bounds__(256) void gather_k(
    const float* __restrict__ X, const int* __restrict__ rp2,
    const int2* __restrict__ pw, float* __restrict__ out, int N) {
    int node = blockIdx.x * 4 + (threadIdx.x >> 6);
    if (node >= N) return;
    int lane = threadIdx.x & 63;
    int q = lane >> 4, m = lane & 15;

    if (REL) {
        // quarter q handles its own relation segment [beg, eend)
        const int beg = rp2[node * 4 + q];
        const int eend = rp2[node * 4 + q + 1];
        float4 acc = make_float4(0.f, 0.f, 0.f, 0.f);
        int i = beg;
        while (__any(i < eend)) {
#pragma unroll
            for (int t = 0; t < 4; ++t) {
                if (i + t < eend) {
                    int2 e = pw[i + t];
                    float4 xv = *reinterpret_cast<const float4*>(
                        X + (size_t)e.x * 64 + m * 4);
                    fma4(acc, __int_as_float(e.y), xv);
                }
            }
            i += 4;
        }
        *reinterpret_cast<float4*>(out + (size_t)node * 256 + q * 64 + m * 4) = acc;
    } else {
        const int s0 = rp2[node * 4];
        const int s4 = rp2[node * 4 + 4];
        float4 A0 = make_float4(0.f, 0.f, 0.f, 0.f);
        float4 A1 = make_float4(0.f, 0.f, 0.f, 0.f);
        float4 A2 = make_float4(0.f, 0.f, 0.f, 0.f);
        float4 A3 = make_float4(0.f, 0.f, 0.f, 0.f);
        int i = s0 + q;
        for (; i + 12 < s4; i += 16) {  // 4 gathers in flight per quarter
            int2 e0 = pw[i];
            int2 e1 = pw[i + 4];
            int2 e2 = pw[i + 8];
            int2 e3 = pw[i + 12];
            float4 x0 = *reinterpret_cast<const float4*>(X + (size_t)e0.x * 64 + m * 4);
            float4 x1 = *reinterpret_cast<const float4*>(X + (size_t)e1.x * 64 + m * 4);
            float4 x2 = *reinterpret_cast<const float4*>(X + (size_t)e2.x * 64 + m * 4);
            float4 x3 = *reinterpret_cast<const float4*>(X + (size_t)e3.x * 64 + m * 4);
            fma4(A0, __int_as_float(e0.y), x0);
            fma4(A1, __int_as_float(e1.y), x1);
            fma4(A2, __int_as_float(e2.y), x2);
            fma4(A3, __int_as_float(e3.y), x3);
        }
        for (; i + 4 < s4; i += 8) {
            int2 e0 = pw[i];
            int2 e1 = pw[i + 4];
            float4 x0 = *reinterpret_cast<const float4*>(X + (size_t)e0.x * 64 + m * 4);
            float4 x1 = *reinterpret_cast<const float4*>(X + (size_t)e1.x * 64 + m * 4);
            fma4(A0, __int_as_float(e0.y), x0);
            fma4(A1, __int_as_float(e1.y), x1);
        }
        if (i < s4) {
            int2 e0 = pw[i];
            float4 x0 = *reinterpret_cast<const float4*>(X + (size_t)e0.x * 64 + m * 4);
            fma4(A0, __int_as_float(e0.y), x0);
        }
        A0.x += A1.x + A2.x + A3.x;
        A0.y += A1.y + A2.y + A3.y;
        A0.z += A1.z + A2.z + A3.z;
        A0.w += A1.w + A2.w + A3.w;
        A0 = quad_reduce(A0);
        if (q == 0)
            *reinterpret_cast<float4*>(out + (size_t)node * 64 + m * 4) = A0;
    }
}

// ---------------------------------------------------------------------------
// Node-side tiled GEMM (deg from rp2 row bounds).
// MODE 0 (rgcn):  OUT = relu((X@B0 + AGG@B1) / deg)            OUT: N x 64
// MODE 1 (group): OUT = X + alpha*((AGG@B0)/deg + bias)        OUT: N x 64
// MODE 3 (group+head): g = X + alpha*((AGG@B0)/deg + bias);
//                      OUT = g@B1 + bias2                      OUT: N x 32
// ---------------------------------------------------------------------------
template <int MODE>
__global__ __launch_bounds__(256) void node_gemm(
    const float* __restrict__ X, const float* __restrict__ AGG,
    const float* __restrict__ B0, const float* __restrict__ B1,
    const float* __restrict__ bias, const float* __restrict__ bias2,
    const float* __restrict__ alphap, const int* __restrict__ rp2,
    float* __restrict__ OUT, int N) {
    __shared__ float As[64][68];
    __shared__ float Bs[64][64];
    const int tid = threadIdx.x;
    const int tx = tid & 15, ty = tid >> 4;
    const int row0 = blockIdx.x * 64;
    float acc[4][4] = {};

    const int nchunks = (MODE == 0) ? 5 : 1;
    for (int c = 0; c < nchunks; ++c) {
        const float* A;
        int lda;
        const float* B;
        int ldb, bcols;
        if (MODE == 0) {
            if (c == 0) { A = X; lda = 64; B = B0; }
            else        { A = AGG + (c - 1) * 64; lda = 256; B = B1 + (size_t)(c - 1) * 64 * 64; }
            ldb = 64; bcols = 64;
        } else {
            A = AGG; lda = 64; B = B0; ldb = 64; bcols = 64;
        }
        if (c) __syncthreads();
#pragma unroll
        for (int q = 0; q < 4; ++q) {
            int f = q * 256 + tid;
            int r = f >> 4;
            int c4 = (f & 15) << 2;
            float4 v = make_float4(0.f, 0.f, 0.f, 0.f);
            int vr = row0 + r;
            if (vr < N) v = *reinterpret_cast<const float4*>(A + (size_t)vr * lda + c4);
            *reinterpret_cast<float4*>(&As[r][c4]) = v;
            float4 bv = make_float4(0.f, 0.f, 0.f, 0.f);
            if (c4 < bcols) bv = *reinterpret_cast<const float4*>(B + (size_t)r * ldb + c4);
            *reinterpret_cast<float4*>(&Bs[r][c4]) = bv;
        }
        __syncthreads();
#pragma unroll 8
        for (int k = 0; k < 64; ++k) {
            float4 b = *reinterpret_cast<const float4*>(&Bs[k][tx * 4]);
            float a0 = As[ty * 4 + 0][k];
            float a1 = As[ty * 4 + 1][k];
            float a2 = As[ty * 4 + 2][k];
            float a3 = As[ty * 4 + 3][k];
            acc[0][0] += a0 * b.x; acc[0][1] += a0 * b.y; acc[0][2] += a0 * b.z; acc[0][3] += a0 * b.w;
            acc[1][0] += a1 * b.x; acc[1][1] += a1 * b.y; acc[1][2] += a1 * b.z; acc[1][3] += a1 * b.w;
            acc[2][0] += a2 * b.x; acc[2][1] += a2 * b.y; acc[2][2] += a2 * b.z; acc[2][3] += a2 * b.w;
            acc[3][0] += a3 * b.x; acc[3][1] += a3 * b.y; acc[3][2] += a3 * b.z; acc[3][3] += a3 * b.w;
        }
    }

    const float alpha = (MODE == 1 || MODE == 3) ? alphap[0] : 0.f;

    if (MODE == 3) {
        // g = X + alpha*(acc/deg + bias) -> As (LDS); outW -> Bs; then
        // OUT = g @ outW + bias2 (64 -> 32).
        __syncthreads();  // main k-loop done everywhere before As/Bs reuse
#pragma unroll
        for (int i = 0; i < 4; ++i) {
            int vr = row0 + ty * 4 + i;
            float dg = 1.f;
            if (vr < N) dg = fmaxf((float)(rp2[vr * 4 + 4] - rp2[vr * 4]), 1.f);
#pragma unroll
            for (int j = 0; j < 4; ++j) {
                int col = tx * 4 + j;
                float g = 0.f;
                if (vr < N)
                    g = X[(size_t)vr * 64 + col] + alpha * (acc[i][j] / dg + bias[col]);
                As[ty * 4 + i][col] = g;
            }
        }
        // stage outW (64 x 32) into Bs[:][0..31]
#pragma unroll
        for (int t = 0; t < 2; ++t) {
            int idx = tid * 2 + t;        // 512 float4s
            int r = idx >> 3;
            int c4 = (idx & 7) << 2;
            *reinterpret_cast<float4*>(&Bs[r][c4]) =
                *reinterpret_cast<const float4*>(B1 + (size_t)r * 32 + c4);
        }
        __syncthreads();
        float acc2[4][2] = {};
#pragma unroll 8
        for (int k = 0; k < 64; ++k) {
            float b0 = Bs[k][tx * 2];
            float b1 = Bs[k][tx * 2 + 1];
#pragma unroll
            for (int i = 0; i < 4; ++i) {
                float a = As[ty * 4 + i][k];
                acc2[i][0] += a * b0;
                acc2[i][1] += a * b1;
            }
        }
#pragma unroll
        for (int i = 0; i < 4; ++i) {
            int vr = row0 + ty * 4 + i;
            if (vr >= N) continue;
#pragma unroll
            for (int j = 0; j < 2; ++j) {
                int col = tx * 2 + j;
                OUT[(size_t)vr * 32 + col] = acc2[i][j] + bias2[col];
            }
        }
        return;
    }

#pragma unroll
    for (int i = 0; i < 4; ++i) {
        int vr = row0 + ty * 4 + i;
        if (vr >= N) continue;
        float dg = fmaxf((float)(rp2[vr * 4 + 4] - rp2[vr * 4]), 1.f);
#pragma unroll
        for (int j = 0; j < 4; ++j) {
            int col = tx * 4 + j;
            if (MODE == 0) {
                OUT[(size_t)vr * 64 + col] = fmaxf(acc[i][j] / dg, 0.f);
            } else {
                OUT[(size_t)vr * 64 + col] =
                    X[(size_t)vr * 64 + col] + alpha * (acc[i][j] / dg + bias[col]);
            }
        }
    }
}

extern "C" void kernel_launch(void* const* d_in, const int* in_sizes, int n_in,
                              void* d_out, int out_size, void* d_ws, size_t ws_size,
                              hipStream_t stream) {
    const float* x      = (const float*)d_in[0];
    const int*   ei     = (const int*)d_in[1];
    const int*   et     = (const int*)d_in[2];
    const float* ew     = (const float*)d_in[3];
    const float* W1     = (const float*)d_in[4];
    const float* W01    = (const float*)d_in[5];
    const float* alpha1 = (const float*)d_in[6];
    const float* projW1 = (const float*)d_in[7];
    const float* projb1 = (const float*)d_in[8];
    const float* W2     = (const float*)d_in[9];
    const float* W02    = (const float*)d_in[10];
    const float* alpha2 = (const float*)d_in[11];
    const float* projW2 = (const float*)d_in[12];
    const float* projb2 = (const float*)d_in[13];
    const float* outW   = (const float*)d_in[14];
    const float* outb   = (const float*)d_in[15];
    const int N = in_sizes[0] / 64;
    const int E = in_sizes[2];
    const int M = 4 * N;            // (dst, rel) segments
    const int NB = (N + 255) >> 8;  // 256-node dst buckets

    // workspace (4-byte units):
    // bcnt[1024] | bofs[1032] | bcur[1024] | rp2[M+1 (+pad to even)] |
    // pw int2[E] | aggR[N*256] (recA int2[E] + recB int[E] aliased inside,
    // CSR-build only) | h[N*64] | g[N*64]
    int*   bcnt = (int*)d_ws;
    int*   bofs = bcnt + 1024;
    int*   bcur = bofs + 1032;
    int*   rp2  = bcur + 1024;
    int2*  pw   = (int2*)(rp2 + ((M + 2) & ~1));
    float* aggR = (float*)(pw + E);
    int2*  recA = (int2*)aggR;            // alias: dead once gather runs
    int*   recB = (int*)(recA + E);
    float* hbuf = aggR + (size_t)N * 256;
    float* gbuf = hbuf + (size_t)N * 64;

    const int gatherBlocks = (N + 3) / 4;
    const int gemmBlocks = (N + 63) / 64;
    const int pBlocks = (E + PART_EPB - 1) / PART_EPB;

    // ---- CSR build (block-aggregated radix partition, once per call) ----
    hipMemsetAsync(bcnt, 0, 1024 * sizeof(int), stream);
    bucket_hist<<<pBlocks, 256, 0, stream>>>(ei, bcnt, E, NB);
    bucket_scan<<<1, 1024, 0, stream>>>(bcnt, bofs, bcur, NB, E);
    partition<<<pBlocks, 256, 0, stream>>>(ei, et, ew, bcur, recA, recB, E, NB);
    bucket_fill<<<NB, 256, 0, stream>>>(recA, recB, bofs, rp2, pw, N);

    // ---- layer 1 ----
    gather_k<1><<<gatherBlocks, 256, 0, stream>>>(x, rp2, pw, aggR, N);
    node_gemm<0><<<gemmBlocks, 256, 0, stream>>>(x, aggR, W01, W1, nullptr, nullptr, nullptr, rp2, hbuf, N);
    gather_k<0><<<gatherBlocks, 256, 0, stream>>>(hbuf, rp2, pw, aggR, N);
    node_gemm<1><<<gemmBlocks, 256, 0, stream>>>(hbuf, aggR, projW1, nullptr, projb1, nullptr, alpha1, rp2, gbuf, N);

    // ---- layer 2 ----
    gather_k<1><<<gatherBlocks, 256, 0, stream>>>(gbuf, rp2, pw, aggR, N);
    node_gemm<0><<<gemmBlocks, 256, 0, stream>>>(gbuf, aggR, W02, W2, nullptr, nullptr, nullptr, rp2, hbuf, N);
    gather_k<0><<<gatherBlocks, 256, 0, stream>>>(hbuf, rp2, pw, aggR, N);
    // group + head fused: writes N x 32 output directly
    node_gemm<3><<<gemmBlocks, 256, 0, stream>>>(hbuf, aggR, projW2, outW, projb2, outb, alpha2, rp2, (float*)d_out, N);
}